// Round 9
// baseline (203.239 us; speedup 1.0000x reference)
//
#include <hip/hip_runtime.h>
#include <hip/hip_bf16.h>

typedef __attribute__((ext_vector_type(8))) short short8;
typedef __attribute__((ext_vector_type(4))) short short4v;
typedef __attribute__((ext_vector_type(4))) float f32x4;

#define MFMA16(a,b,c) __builtin_amdgcn_mfma_f32_16x16x32_bf16((a),(b),(c),0,0,0)

constexpr int BHn = 32;     // B*NH
constexpr int Tn  = 2048;
constexpr int Nn  = 512;
constexpr int Dn  = 128;
constexpr int CHn = 64;     // chunk length
constexpr int NCH = Tn / CHn;

static __device__ __forceinline__ unsigned short f2b(float x){
  __hip_bfloat16 h = __float2bfloat16(x);
  return *reinterpret_cast<unsigned short*>(&h);
}

// ---------------- Kernel 1: RoPE(Q) -> bf16 in QUAD-INTERLEAVED layout ----------------
// QRq[bh][t>>2][n][t&3]: shorts addr = (t>>2)*2048 + n*4 + (t&3). Consecutive dt for a
// fixed n are contiguous -> state-wave B-frags become two 8B loads instead of 8 u16.
__global__ __launch_bounds__(256) void rope_k(const float* __restrict__ Q,
                                              const float* __restrict__ freqs,
                                              unsigned short* __restrict__ QRq){
  int tq  = blockIdx.x & 511;          // t-quad [0,512)
  int bh0 = (blockIdx.x >> 9) << 3;    // bh group of 8
  int np  = threadIdx.x;               // pair index n in [0,256)
  float f1 = freqs[np], f2 = freqs[np + 256];
  float s1[4], c1[4], s2[4], c2[4];
  #pragma unroll
  for (int i = 0; i < 4; ++i){
    float tf = (float)(tq * 4 + i);
    sincosf(tf * f1, &s1[i], &c1[i]);
    sincosf(tf * f2, &s2[i], &c2[i]);
  }
  for (int b = 0; b < 8; ++b){
    int bh = bh0 + b;
    const float* qp = Q + (size_t)bh * Tn * Nn + (size_t)(tq * 4) * Nn + np;
    short4v o1, o2;
    #pragma unroll
    for (int i = 0; i < 4; ++i){
      float q1 = qp[(size_t)i * Nn], q2 = qp[(size_t)i * Nn + 256];
      o1[i] = (short)f2b(q1 * c1[i] - q2 * s1[i]);   // n = np
      o2[i] = (short)f2b(q2 * c2[i] + q1 * s2[i]);   // n = np+256
    }
    unsigned short* dst = QRq + (size_t)bh * Tn * Nn + (size_t)tq * 2048;
    *reinterpret_cast<short4v*>(dst + np * 4)         = o1;   // coalesced 8B stores
    *reinterpret_cast<short4v*>(dst + (np + 256) * 4) = o2;
  }
}

// ---------------- LDS fragment loaders (swizzled) ----------------
// standard swizzle: col ^= (row&7)<<3 (16B granules)
__device__ __forceinline__ short8 ldfrag(const unsigned short* buf, int rowbase, int k0, int ld, int lane){
  int row = rowbase + (lane & 15);
  int col = (k0 + ((lane >> 4) << 3)) ^ ((row & 7) << 3);
  return *reinterpret_cast<const short8*>(buf + row * ld + col);
}

// ---------------- staging: one QRq uint4 (2 n x 4 dt) -> row-major swizzled Rs ----------
// uint4 shorts s0..s7 = (n0,t0..t3),(n0+1,t0..t3). out_k = s_k | s_{k+4}<<16 -> Rs[dt0+k][n0..n0+1].
__device__ __forceinline__ void stage_q(unsigned short* Rs, uint4 v, int dt0, int n0){
  unsigned w0 = v.x, w1 = v.y, w2 = v.z, w3 = v.w;
  unsigned o0 = (w0 & 0xffffu) | (w2 << 16);
  unsigned o1 = (w0 >> 16)     | (w2 & 0xffff0000u);
  unsigned o2 = (w1 & 0xffffu) | (w3 << 16);
  unsigned o3 = (w1 >> 16)     | (w3 & 0xffff0000u);
  *reinterpret_cast<unsigned*>(&Rs[(dt0    ) * 512 + (n0 ^ (((dt0    ) & 7) << 3))]) = o0;
  *reinterpret_cast<unsigned*>(&Rs[(dt0 + 1) * 512 + (n0 ^ (((dt0 + 1) & 7) << 3))]) = o1;
  *reinterpret_cast<unsigned*>(&Rs[(dt0 + 2) * 512 + (n0 ^ (((dt0 + 2) & 7) << 3))]) = o2;
  *reinterpret_cast<unsigned*>(&Rs[(dt0 + 3) * 512 + (n0 ^ (((dt0 + 3) & 7) << 3))]) = o3;
}

// ---------------- Kernel 2: chunked linear-attention scan, 8 waves, 2 barriers/chunk ----
// Waves 0-3: compute (P~ tiles + one oacc i-tile each) — frags from LDS Rs (dense stream).
// Waves 4-7: state, 8 n-tiles each — B-frags via two 8B global loads from quad-interleaved
// QRq (L2-hot chunk; 4x fewer gather instructions than u16 gather).
__global__ __launch_bounds__(512, 1) void lattn_main(
    const unsigned short* __restrict__ QRq,  // bf16 quad-interleaved (BH,T/4,N,4)
    const float* __restrict__ V,             // (BH,T,D)
    const float* __restrict__ S_prev,        // (BH,N,D)
    const float* __restrict__ gammap,
    float* __restrict__ Out,                 // (BH,T,D)
    float* __restrict__ Sfin)                // (BH,N,D)
{
  __shared__ __align__(16) unsigned short Rs [64 * 512];   // R row-major [dt][n] (64 KB)
  __shared__ __align__(16) unsigned short SbTs[16 * 512];  // bf16(S_start)^T [d][n] (16 KB)
  __shared__ __align__(16) unsigned short VTs[2][16 * 64]; // Vt^T [d][dt] double-buffered
  __shared__ __align__(16) unsigned short Ps [64 * 64];    // P~ [i][j]
  __shared__ float gpow[65], gpinv[65];

  const int tid  = threadIdx.x;
  const int w    = tid >> 6;
  const int lane = tid & 63;
  const int bh   = blockIdx.x & 31;   // same bh -> same XCD (blockIdx%8 == bh%8)
  const int dch  = blockIdx.x >> 5;   // 8 d-slices of 16
  const int d0   = dch * 16;
  const float g  = gammap[0];

  const unsigned short* QRbh = QRq + (size_t)bh * Tn * Nn;
  const float* Vbh = V + (size_t)bh * Tn * Dn;

  // ---- prologue ----
  if (tid < 65){
    gpow[tid]  = powf(g,  (float)tid);
    gpinv[tid] = powf(g, -(float)tid);
  }
  #pragma unroll
  for (int i = tid; i < 64 * 64; i += 512) Ps[i] = 0;  // strictly-upper tiles stay 0 forever

  f32x4 st[8];  // waves 4-7: state S^T[d][n], 8 n-tiles each (D-frag: col=n=lane&15, row=d=4*(lane>>4)+r)
  if (w >= 4){
    int r0 = (w - 4) * 8;
    #pragma unroll
    for (int j = 0; j < 8; ++j){
      int n = (r0 + j) * 16 + (lane & 15);
      const float* sp = S_prev + (size_t)bh * Nn * Dn + (size_t)n * Dn + d0 + ((lane >> 4) << 2);
      st[j] = *reinterpret_cast<const f32x4*>(sp);
    }
  }
  __syncthreads();   // gpow/gpinv ready
  const float g64 = gpow[64];

  // ---- stage chunk 0 ----
  {
    #pragma unroll
    for (int i = 0; i < 8; ++i){
      int p = tid + i * 512;                 // uint4 index in chunk (4096 total)
      int tql = p >> 8, n0 = (p & 255) << 1;
      uint4 v = *reinterpret_cast<const uint4*>(QRbh + (size_t)tql * 2048 + n0 * 4);
      stage_q(Rs, v, tql << 2, n0);
    }
    {
      int dtv = tid >> 3, dp = (tid & 7) << 1;
      const float* vp = Vbh + (size_t)dtv * Dn + d0 + dp;
      float sc = gpinv[dtv];
      VTs[0][ dp      * 64 + (dtv ^ (( dp      & 7) << 3))] = f2b(vp[0] * sc);
      VTs[0][(dp + 1) * 64 + (dtv ^ (((dp + 1) & 7) << 3))] = f2b(vp[1] * sc);
    }
    if (w >= 4){
      int r0 = (w - 4) * 8;
      #pragma unroll
      for (int j = 0; j < 8; ++j){
        int n  = (r0 + j) * 16 + (lane & 15);
        int dl = (lane >> 4) << 2;
        #pragma unroll
        for (int r = 0; r < 4; ++r){
          int d = dl + r;
          SbTs[d * 512 + (n ^ ((d & 7) << 3))] = f2b(st[j][r]);
        }
      }
    }
  }
  __syncthreads();   // chunk 0 resident

  for (int c = 0; c < NCH; ++c){
    const int t0 = c * CHn;
    const int vb = c & 1;
    const bool pf = (c + 1 < NCH);
    const unsigned short* Qc = QRbh + (size_t)t0 * Nn;   // this chunk's QRq slice (L2-hot)

    // ---- prefetch chunk c+1 into registers (latency hides under Ph1 compute) ----
    uint4 rq[8];
    float va0 = 0.f, va1 = 0.f;
    const int dtv_ = tid >> 3;
    if (pf){
      const unsigned short* QRc = QRbh + (size_t)(t0 + CHn) * Nn;
      #pragma unroll
      for (int i = 0; i < 8; ++i){
        int p = tid + i * 512;
        int tql = p >> 8, n0 = (p & 255) << 1;
        rq[i] = *reinterpret_cast<const uint4*>(QRc + (size_t)tql * 2048 + n0 * 4);
      }
      const float* vp = Vbh + (size_t)(t0 + CHn + dtv_) * Dn + d0 + ((tid & 7) << 1);
      va0 = vp[0]; va1 = vp[1];
    }

    // ================= Ph1 =================
    f32x4 oacc = {0.f, 0.f, 0.f, 0.f};
    if (w < 4){
      // G1: P~ lower/diag tiles + G2': OutT[d][i] += SbT-frag x R-colfrag (fused k-loop)
      f32x4 p0 = {0.f,0.f,0.f,0.f}, p1 = p0, p2 = p0;
      for (int kb = 0; kb < 16; ++kb){
        int k0 = kb * 32;
        short8 fs = ldfrag(SbTs, 0, k0, 512, lane);
        if (w == 0){
          short8 f0 = ldfrag(Rs,  0, k0, 512, lane);
          short8 f1 = ldfrag(Rs, 16, k0, 512, lane);
          p0   = MFMA16(f0, f0, p0);      // (0,0)
          p1   = MFMA16(f1, f0, p1);      // (1,0)
          p2   = MFMA16(f1, f1, p2);      // (1,1)
          oacc = MFMA16(fs, f0, oacc);    // i-tile 0
        } else if (w == 1){
          short8 f0 = ldfrag(Rs,  0, k0, 512, lane);
          short8 f1 = ldfrag(Rs, 16, k0, 512, lane);
          short8 f2 = ldfrag(Rs, 32, k0, 512, lane);
          p0   = MFMA16(f2, f0, p0);      // (2,0)
          p1   = MFMA16(f2, f1, p1);      // (2,1)
          p2   = MFMA16(f2, f2, p2);      // (2,2)
          oacc = MFMA16(fs, f2, oacc);    // i-tile 2
        } else if (w == 2){
          short8 f0 = ldfrag(Rs,  0, k0, 512, lane);
          short8 f1 = ldfrag(Rs, 16, k0, 512, lane);
          short8 f3 = ldfrag(Rs, 48, k0, 512, lane);
          p0   = MFMA16(f3, f0, p0);      // (3,0)
          p1   = MFMA16(f3, f1, p1);      // (3,1)
          oacc = MFMA16(fs, f3, oacc);    // i-tile 3
        } else {
          short8 f1 = ldfrag(Rs, 16, k0, 512, lane);
          short8 f2 = ldfrag(Rs, 32, k0, 512, lane);
          short8 f3 = ldfrag(Rs, 48, k0, 512, lane);
          p0   = MFMA16(f3, f2, p0);      // (3,2)
          p1   = MFMA16(f3, f3, p1);      // (3,3)
          oacc = MFMA16(fs, f1, oacc);    // i-tile 1
        }
      }
      // epilogue: P~[i][j] = (j<i) ? gamma^i * acc : 0   (C-frag: col=j=lane&15, row=i=4*(lane>>4)+r)
      int tI[3], tJ[3], nt;
      if      (w == 0){ tI[0]=0; tJ[0]=0; tI[1]=1; tJ[1]=0; tI[2]=1; tJ[2]=1; nt = 3; }
      else if (w == 1){ tI[0]=2; tJ[0]=0; tI[1]=2; tJ[1]=1; tI[2]=2; tJ[2]=2; nt = 3; }
      else if (w == 2){ tI[0]=3; tJ[0]=0; tI[1]=3; tJ[1]=1; tI[2]=0; tJ[2]=0; nt = 2; }
      else            { tI[0]=3; tJ[0]=2; tI[1]=3; tJ[1]=3; tI[2]=0; tJ[2]=0; nt = 2; }
      f32x4 pacc[3] = {p0, p1, p2};
      for (int q = 0; q < nt; ++q){
        int j  = tJ[q] * 16 + (lane & 15);
        int i0 = tI[q] * 16 + ((lane >> 4) << 2);
        #pragma unroll
        for (int r = 0; r < 4; ++r){
          int i = i0 + r;
          float v = (j < i) ? pacc[q][r] * gpow[i] : 0.f;
          Ps[i * 64 + (j ^ ((i & 7) << 3))] = f2b(v);
        }
      }
    } else {
      // G4': state update S^T += VTs(A) x QRq-quad-gather(B), then *gamma^64
      int r0 = (w - 4) * 8;
      #pragma unroll
      for (int ks = 0; ks < 2; ++ks){
        short8 av = ldfrag(VTs[vb], 0, ks * 32, 64, lane);
        #pragma unroll
        for (int j = 0; j < 8; ++j){
          int n   = (r0 + j) * 16 + (lane & 15);
          int dt0 = ks * 32 + ((lane >> 4) << 3);
          const unsigned short* bp = Qc + (size_t)(dt0 >> 2) * 2048 + n * 4;
          short4v lo = *reinterpret_cast<const short4v*>(bp);          // dt0..dt0+3
          short4v hi = *reinterpret_cast<const short4v*>(bp + 2048);   // dt0+4..dt0+7
          short8 bn = __builtin_shufflevector(lo, hi, 0, 1, 2, 3, 4, 5, 6, 7);
          st[j] = MFMA16(av, bn, st[j]);
        }
      }
      #pragma unroll
      for (int j = 0; j < 8; ++j)
        #pragma unroll
        for (int r = 0; r < 4; ++r) st[j][r] *= g64;
    }
    __syncthreads();

    // ================= Ph2: out store + staging for c+1 =================
    if (w >= 4){
      // SbT for chunk c+1 (st already updated+scaled = S_start(c+1))
      int r0 = (w - 4) * 8;
      #pragma unroll
      for (int j = 0; j < 8; ++j){
        int n  = (r0 + j) * 16 + (lane & 15);
        int dl = (lane >> 4) << 2;
        #pragma unroll
        for (int r = 0; r < 4; ++r){
          int d = dl + r;
          SbTs[d * 512 + (n ^ ((d & 7) << 3))] = f2b(st[j][r]);
        }
      }
    } else {
      // out = gamma^i * inter + intra
      const int itl = (w == 0) ? 0 : (w == 1) ? 2 : (w == 2) ? 3 : 1;
      float gi = gpow[itl * 16 + (lane & 15)];   // inter term scale gamma^i (col = i)
      #pragma unroll
      for (int r = 0; r < 4; ++r) oacc[r] *= gi;
      #pragma unroll
      for (int ks = 0; ks < 2; ++ks){
        short8 av = ldfrag(VTs[vb], 0, ks * 32, 64, lane);
        short8 bp = ldfrag(Ps, itl * 16, ks * 32, 64, lane);
        oacc = MFMA16(av, bp, oacc);   // OutT[d][i] += sum_j VT[d][j] * P~[i][j]
      }
      int ti = t0 + itl * 16 + (lane & 15);
      float* op = Out + (size_t)bh * Tn * Dn + (size_t)ti * Dn + d0 + ((lane >> 4) << 2);
      *reinterpret_cast<f32x4*>(op) = oacc;
    }
    // staging writes for chunk c+1 from prefetched registers (all waves; Rs dead)
    if (pf){
      #pragma unroll
      for (int i = 0; i < 8; ++i){
        int p = tid + i * 512;
        int tql = p >> 8, n0 = (p & 255) << 1;
        stage_q(Rs, rq[i], tql << 2, n0);
      }
      int dp = (tid & 7) << 1;
      float sc = gpinv[dtv_];
      VTs[vb ^ 1][ dp      * 64 + (dtv_ ^ (( dp      & 7) << 3))] = f2b(va0 * sc);
      VTs[vb ^ 1][(dp + 1) * 64 + (dtv_ ^ (((dp + 1) & 7) << 3))] = f2b(va1 * sc);
    }
    __syncthreads();
  }

  // ---- epilogue: final state ----
  if (w >= 4){
    int r0 = (w - 4) * 8;
    #pragma unroll
    for (int j = 0; j < 8; ++j){
      int n = (r0 + j) * 16 + (lane & 15);
      float* sp = Sfin + (size_t)bh * Nn * Dn + (size_t)n * Dn + d0 + ((lane >> 4) << 2);
      *reinterpret_cast<f32x4*>(sp) = st[j];
    }
  }
}

extern "C" void kernel_launch(void* const* d_in, const int* in_sizes, int n_in,
                              void* d_out, int out_size, void* d_ws, size_t ws_size,
                              hipStream_t stream){
  const float* Q      = (const float*)d_in[0];
  const float* V      = (const float*)d_in[1];
  const float* S_prev = (const float*)d_in[2];
  const float* freqs  = (const float*)d_in[3];
  const float* gamma  = (const float*)d_in[4];
  float* Out  = (float*)d_out;
  float* Sfin = Out + (size_t)BHn * Tn * Dn;
  unsigned short* QRq = (unsigned short*)d_ws;   // 64 MB bf16 scratch (quad-interleaved)

  rope_k<<<2048, 256, 0, stream>>>(Q, freqs, QRq);
  lattn_main<<<256, 512, 0, stream>>>(QRq, V, S_prev, gamma, Out, Sfin);
}